// Round 2
// baseline (476.572 us; speedup 1.0000x reference)
//
#include <hip/hip_runtime.h>
#include <hip/hip_bf16.h>

#define N_NODES 100000

typedef unsigned short ushort_t;
typedef __attribute__((ext_vector_type(8))) short short8;
typedef __attribute__((ext_vector_type(4))) float f32x4;

// ---------------------------------------------------------------------------
// helpers
// ---------------------------------------------------------------------------
static __device__ __forceinline__ ushort_t f2bf(float f) {
    unsigned u = __float_as_uint(f);
    unsigned r = u + 0x7FFFu + ((u >> 16) & 1u);   // round-to-nearest-even
    return (ushort_t)(r >> 16);
}
static __device__ __forceinline__ float bf2f(ushort_t h) {
    return __uint_as_float(((unsigned)h) << 16);
}

// split 8 contiguous fp32 into hi/lo bf16 fragments
static __device__ __forceinline__ void split8(const float* __restrict__ xp,
                                              short8& hi, short8& lo) {
    float4 x0 = *(const float4*)xp;
    float4 x1 = *(const float4*)(xp + 4);
    float xs[8] = {x0.x, x0.y, x0.z, x0.w, x1.x, x1.y, x1.z, x1.w};
    #pragma unroll
    for (int j = 0; j < 8; ++j) {
        ushort_t h = f2bf(xs[j]);
        hi[j] = (short)h;
        lo[j] = (short)f2bf(xs[j] - bf2f(h));
    }
}

// unpack-accumulate one u32 (2 bf16) into two fp32 accumulators
static __device__ __forceinline__ void acc_u32(unsigned w, float& a0, float& a1) {
    a0 += __uint_as_float(w << 16);
    a1 += __uint_as_float(w & 0xFFFF0000u);
}

// ---------------------------------------------------------------------------
// CSR build: histogram -> 3-phase scan -> bucket-binning -> exclusive scatter
// ---------------------------------------------------------------------------
__global__ __launch_bounds__(256) void hist_kernel(const int* __restrict__ dst,
                                                   int* __restrict__ deg, int E) {
    int e = blockIdx.x * 256 + threadIdx.x;
    if (e < E) atomicAdd(&deg[__builtin_nontemporal_load(&dst[e])], 1);
}

// phase 1: per-block (1024-elem segment) total
__global__ __launch_bounds__(256) void scan_partial_sums(const int* __restrict__ deg,
                                                         int* __restrict__ partials, int N) {
    __shared__ int wsums[4];
    int tid = threadIdx.x, lane = tid & 63, wv = tid >> 6;
    int i0 = blockIdx.x * 1024 + tid * 4;
    int s = 0;
    #pragma unroll
    for (int j = 0; j < 4; ++j) {
        int i = i0 + j;
        if (i < N) s += deg[i];
    }
    #pragma unroll
    for (int off = 32; off > 0; off >>= 1) s += __shfl_xor(s, off, 64);
    if (lane == 0) wsums[wv] = s;
    __syncthreads();
    if (tid == 0)
        partials[blockIdx.x] = wsums[0] + wsums[1] + wsums[2] + wsums[3];
}

// phase 2: single block scans NB (<=256) partials -> exclusive, writes row_ptr[N]
__global__ __launch_bounds__(256) void scan_partials(int* __restrict__ partials, int NB,
                                                     int* __restrict__ row_ptr, int N) {
    __shared__ int wsums[4];
    int tid = threadIdx.x, lane = tid & 63, wv = tid >> 6;
    int v = (tid < NB) ? partials[tid] : 0;
    int x = v;
    #pragma unroll
    for (int off = 1; off < 64; off <<= 1) {
        int y = __shfl_up(x, off, 64);
        if (lane >= off) x += y;
    }
    if (lane == 63) wsums[wv] = x;
    __syncthreads();
    int woff = 0;
    for (int w = 0; w < wv; ++w) woff += wsums[w];
    int incl = x + woff;
    if (tid < NB) partials[tid] = incl - v;          // exclusive
    if (tid == NB - 1) row_ptr[N] = incl;            // grand total
}

// phase 3: emit row_ptr/cursor/invd; also init per-bucket cursor gcur
__global__ __launch_bounds__(256) void scan_emit(const int* __restrict__ deg,
                                                 const int* __restrict__ partials,
                                                 int* __restrict__ row_ptr,
                                                 int* __restrict__ cursor,
                                                 float* __restrict__ inv_deg,
                                                 int* __restrict__ gcur, int N) {
    __shared__ int wsums[4];
    int tid = threadIdx.x, lane = tid & 63, wv = tid >> 6;
    int i0 = blockIdx.x * 1024 + tid * 4;
    int d[4];
    #pragma unroll
    for (int j = 0; j < 4; ++j) {
        int i = i0 + j;
        d[j] = (i < N) ? deg[i] : 0;
    }
    int s = d[0] + d[1] + d[2] + d[3];
    int x = s;
    #pragma unroll
    for (int off = 1; off < 64; off <<= 1) {
        int y = __shfl_up(x, off, 64);
        if (lane >= off) x += y;
    }
    if (lane == 63) wsums[wv] = x;
    __syncthreads();
    int woff = 0;
    for (int w = 0; w < wv; ++w) woff += wsums[w];
    int run = partials[blockIdx.x] + woff + x - s;   // exclusive prefix of elem i0
    #pragma unroll
    for (int j = 0; j < 4; ++j) {
        int i = i0 + j;
        if (i < N) {
            row_ptr[i] = run;
            cursor[i]  = run;
            inv_deg[i] = 1.0f / (float)(d[j] > 0 ? d[j] : 1);
            if ((i & 255) == 0) gcur[i >> 8] = run;   // bucket staging base
            run += d[j];
        }
    }
}

// Phase A: bin (src,dst) pairs into bucket-ordered staging (bucket = dst>>8).
#define MAXBUCK 512
__global__ __launch_bounds__(256) void bin_pairs(const int* __restrict__ src,
                                                 const int* __restrict__ dst,
                                                 int* __restrict__ gcur,
                                                 long long* __restrict__ staged,
                                                 int E, int NBUCK, int C) {
    __shared__ int cnt[MAXBUCK];
    int tid = threadIdx.x;
    int e0 = blockIdx.x * C;
    int e1 = min(e0 + C, E);
    for (int b = tid; b < NBUCK; b += 256) cnt[b] = 0;
    __syncthreads();
    for (int e = e0 + tid; e < e1; e += 256) {
        int d = __builtin_nontemporal_load(&dst[e]);
        atomicAdd(&cnt[d >> 8], 1);
    }
    __syncthreads();
    for (int b = tid; b < NBUCK; b += 256) {
        int c = cnt[b];
        cnt[b] = (c > 0) ? atomicAdd(&gcur[b], c) : 0;   // now LDS cursor = global pos
    }
    __syncthreads();
    for (int e = e0 + tid; e < e1; e += 256) {
        int d = __builtin_nontemporal_load(&dst[e]);
        int s = __builtin_nontemporal_load(&src[e]);
        int p = atomicAdd(&cnt[d >> 8], 1);
        staged[p] = ((long long)d << 32) | (unsigned)s;   // hi=dst, lo=src
    }
}

// Phase B: one block per bucket; scatter within a private ~16KB edge_src window
__global__ __launch_bounds__(256) void scatter_bucket(const long long* __restrict__ staged,
                                                      const int* __restrict__ row_ptr,
                                                      int* __restrict__ cursor,
                                                      int* __restrict__ edge_src,
                                                      int N) {
    int b = blockIdx.x;
    int lo = b << 8;
    int hiN = min((b + 1) << 8, N);
    int gstart = row_ptr[lo];
    int gend   = row_ptr[hiN];
    for (int p = gstart + threadIdx.x; p < gend; p += 256) {
        long long pr = __builtin_nontemporal_load(&staged[p]);
        int d = (int)(pr >> 32);
        int s = (int)(pr & 0xFFFFFFFFll);
        int pos = atomicAdd(&cursor[d], 1);
        edge_src[pos] = s;
    }
}

// ---------------------------------------------------------------------------
// Weight pre-pack (all 6 matrices in ONE launch)
// ---------------------------------------------------------------------------
__global__ __launch_bounds__(256) void pack_all(
        const float* __restrict__ W0, const float* __restrict__ W1,
        const float* __restrict__ W2, const float* __restrict__ W3,
        const float* __restrict__ W4, const float* __restrict__ W5,
        ushort_t* H0, ushort_t* L0, ushort_t* H1, ushort_t* L1,
        ushort_t* H2, ushort_t* L2, ushort_t* H3, ushort_t* L3,
        ushort_t* H4, ushort_t* L4, ushort_t* H5, ushort_t* L5) {
    int b = blockIdx.x;
    const float* W; ushort_t* Hi; ushort_t* Lo; int K, NS, base;
    if (b < 8)       { W = W0; Hi = H0; Lo = L0; K = 128; NS = 128; base = 0;  }
    else if (b < 16) { W = W1; Hi = H1; Lo = L1; K = 128; NS = 128; base = 8;  }
    else if (b < 20) { W = W2; Hi = H2; Lo = L2; K = 128; NS = 64;  base = 16; }
    else if (b < 24) { W = W3; Hi = H3; Lo = L3; K = 128; NS = 64;  base = 20; }
    else if (b < 26) { W = W4; Hi = H4; Lo = L4; K = 64;  NS = 64;  base = 24; }
    else             { W = W5; Hi = H5; Lo = L5; K = 64;  NS = 64;  base = 26; }
    int tid = (b - base) * 256 + threadIdx.x;
    if (tid >= (K * NS) / 8) return;
    int l  = tid & 63;
    int fl = tid >> 6;
    int NT = NS / 16;
    int t = fl % NT, s = fl / NT;
    ushort_t hs[8], ls[8];
    #pragma unroll
    for (int j = 0; j < 8; ++j) {
        int k = s * 32 + (l >> 4) * 8 + j;
        int n = t * 16 + (l & 15);
        float w = W[(size_t)k * NS + n];
        ushort_t h = f2bf(w);
        hs[j] = h;
        ls[j] = f2bf(w - bf2f(h));
    }
    #pragma unroll
    for (int j = 0; j < 8; ++j) {
        Hi[(size_t)tid * 8 + j] = hs[j];
        Lo[(size_t)tid * 8 + j] = ls[j];
    }
}

// ---------------------------------------------------------------------------
// MFMA dual GEMM (split-bf16, fp32-grade) with LDS-transposed vector epilogue:
//   S[M,NS]  = X @ Ws + bias  (fp32 out, float4 stores)
//   Zb[M,NS] = X @ Wn         (bf16 out, uint2 stores)
// Per-wave private LDS staging (stride 20 words -> max 2-way bank alias, free;
// no barriers needed). R8 lesson: scalar epilogue stores caused 1.6x HBM write
// amplification + vmcnt stalls (123 MB vs 77 ideal, all pipes <25% busy).
// ---------------------------------------------------------------------------
template <int K, int NS>
__global__ __launch_bounds__(256) void mfma_gemm(const float* __restrict__ X,
                                                 const ushort_t* __restrict__ BsHi,
                                                 const ushort_t* __restrict__ BsLo,
                                                 const ushort_t* __restrict__ BnHi,
                                                 const ushort_t* __restrict__ BnLo,
                                                 const float* __restrict__ bias,
                                                 float* __restrict__ S,
                                                 ushort_t* __restrict__ Zb,
                                                 int M) {
    constexpr int KS = K / 32;      // mfma k-steps
    constexpr int NT = NS / 16;     // n-tiles
    __shared__ float ldsS[4][32 * 20];   // per-wave private transpose buffers
    __shared__ float ldsZ[4][32 * 20];
    int tid = threadIdx.x;
    int lane = tid & 63, w = tid >> 6;
    int baseM = blockIdx.x * 128 + w * 32;
    int rIn = lane & 15, q = lane >> 4;
    float* bufS = ldsS[w];
    float* bufZ = ldsZ[w];

    // ---- load + split all A fragments for this wave's 32 rows ----
    short8 Ahi[KS][2], Alo[KS][2];
    #pragma unroll
    for (int s = 0; s < KS; ++s) {
        #pragma unroll
        for (int mt = 0; mt < 2; ++mt) {
            int gm = baseM + mt * 16 + rIn;
            if (gm < M) {
                split8(&X[(size_t)gm * K + s * 32 + q * 8], Ahi[s][mt], Alo[s][mt]);
            } else {
                #pragma unroll
                for (int j = 0; j < 8; ++j) { Ahi[s][mt][j] = 0; Alo[s][mt][j] = 0; }
            }
        }
    }

    // ---- loop n-tiles; stream B frags from L2; 12 MFMA per (s,t) ----
    for (int t = 0; t < NT; ++t) {
        f32x4 aS0 = {0.f, 0.f, 0.f, 0.f}, aS1 = {0.f, 0.f, 0.f, 0.f};
        f32x4 aZ0 = {0.f, 0.f, 0.f, 0.f}, aZ1 = {0.f, 0.f, 0.f, 0.f};
        #pragma unroll
        for (int s = 0; s < KS; ++s) {
            size_t fo = ((size_t)(s * NT + t) * 64 + lane) * 8;
            short8 bsh = *(const short8*)&BsHi[fo];
            short8 bsl = *(const short8*)&BsLo[fo];
            short8 bnh = *(const short8*)&BnHi[fo];
            short8 bnl = *(const short8*)&BnLo[fo];
            aS0 = __builtin_amdgcn_mfma_f32_16x16x32_bf16(Ahi[s][0], bsh, aS0, 0, 0, 0);
            aS0 = __builtin_amdgcn_mfma_f32_16x16x32_bf16(Alo[s][0], bsh, aS0, 0, 0, 0);
            aS0 = __builtin_amdgcn_mfma_f32_16x16x32_bf16(Ahi[s][0], bsl, aS0, 0, 0, 0);
            aS1 = __builtin_amdgcn_mfma_f32_16x16x32_bf16(Ahi[s][1], bsh, aS1, 0, 0, 0);
            aS1 = __builtin_amdgcn_mfma_f32_16x16x32_bf16(Alo[s][1], bsh, aS1, 0, 0, 0);
            aS1 = __builtin_amdgcn_mfma_f32_16x16x32_bf16(Ahi[s][1], bsl, aS1, 0, 0, 0);
            aZ0 = __builtin_amdgcn_mfma_f32_16x16x32_bf16(Ahi[s][0], bnh, aZ0, 0, 0, 0);
            aZ0 = __builtin_amdgcn_mfma_f32_16x16x32_bf16(Alo[s][0], bnh, aZ0, 0, 0, 0);
            aZ0 = __builtin_amdgcn_mfma_f32_16x16x32_bf16(Ahi[s][0], bnl, aZ0, 0, 0, 0);
            aZ1 = __builtin_amdgcn_mfma_f32_16x16x32_bf16(Ahi[s][1], bnh, aZ1, 0, 0, 0);
            aZ1 = __builtin_amdgcn_mfma_f32_16x16x32_bf16(Alo[s][1], bnh, aZ1, 0, 0, 0);
            aZ1 = __builtin_amdgcn_mfma_f32_16x16x32_bf16(Ahi[s][1], bnl, aZ1, 0, 0, 0);
        }
        // ---- epilogue: C layout (col=rIn, row=q*4+r) -> LDS -> float4 stores
        #pragma unroll
        for (int r = 0; r < 4; ++r) {
            bufS[(q * 4 + r) * 20 + rIn]        = aS0[r];
            bufS[(16 + q * 4 + r) * 20 + rIn]   = aS1[r];
            bufZ[(q * 4 + r) * 20 + rIn]        = aZ0[r];
            bufZ[(16 + q * 4 + r) * 20 + rIn]   = aZ1[r];
        }
        int row = lane >> 2;            // 0..15
        int cq  = lane & 3;
        int col = t * 16 + cq * 4;
        float4 bv = *(const float4*)&bias[col];
        #pragma unroll
        for (int half = 0; half < 2; ++half) {
            int gm = baseM + half * 16 + row;
            float4 v = *(float4*)&bufS[(half * 16 + row) * 20 + cq * 4];
            float4 z = *(float4*)&bufZ[(half * 16 + row) * 20 + cq * 4];
            if (gm < M) {
                float4 o;
                o.x = v.x + bv.x; o.y = v.y + bv.y;
                o.z = v.z + bv.z; o.w = v.w + bv.w;
                *(float4*)&S[(size_t)gm * NS + col] = o;
                uint2 o2;
                o2.x = (unsigned)f2bf(z.x) | ((unsigned)f2bf(z.y) << 16);
                o2.y = (unsigned)f2bf(z.z) | ((unsigned)f2bf(z.w) << 16);
                *(uint2*)&Zb[(size_t)gm * NS + col] = o2;
            }
        }
    }
}

// ---------------------------------------------------------------------------
// Aggregate with bf16 Z: out[n,f] = act( S[n,f] + inv_deg[n]*sum Z[src,f] )
// R9 restructure: 16 lanes per node for BOTH D=128 (uint4/16B gathers) and
// D=64 (uint2/8B gathers); 8-edge fully-predicated unroll (no serial tail,
// 8 gathers in flight per lane); dual pairwise accumulators (acc[2][PF],
// constant indices only -> stays in registers); nontemporal hints on the
// stream-once S / edge_src reads to preserve L2 residency of hot Z lines.
// ACT: 0 = relu, 1 = softmax across the 16-lane group (D=64 only)
// ---------------------------------------------------------------------------
template <int D, int ACT>
__global__ __launch_bounds__(256) void agg_kernel(const float* __restrict__ S,
                                                  const ushort_t* __restrict__ Zb,
                                                  const int* __restrict__ row_ptr,
                                                  const int* __restrict__ edge_src,
                                                  const float* __restrict__ inv_deg,
                                                  float* __restrict__ out, int N) {
    constexpr int G  = 16;             // lanes per node
    constexpr int PF = D / G;          // floats per lane: 8 (D=128) / 4 (D=64)
    constexpr int NV = PF / 4;         // float4s per lane: 2 / 1
    constexpr int NG = 256 / G;        // 16 nodes per block
    constexpr int U  = 8;              // edge unroll (fully predicated)
    int tid = threadIdx.x;
    int g = tid >> 4, fl = tid & 15;
    int n = blockIdx.x * NG + g;
    if (n >= N) return;
    int beg = row_ptr[n], end = row_ptr[n + 1];

    float acc[2][PF];
    #pragma unroll
    for (int i = 0; i < PF; ++i) { acc[0][i] = 0.f; acc[1][i] = 0.f; }

    const char* zlane = (const char*)Zb + fl * (PF * 2);   // lane byte offset in row

    for (int j = beg; j < end; j += U) {
        int srcs[U];
        #pragma unroll
        for (int k = 0; k < U; ++k)
            srcs[k] = (j + k < end) ? __builtin_nontemporal_load(&edge_src[j + k]) : -1;

        if constexpr (PF == 8) {
            uint4 u[U];
            #pragma unroll
            for (int k = 0; k < U; ++k) {
                u[k] = make_uint4(0u, 0u, 0u, 0u);
                if (srcs[k] >= 0)
                    u[k] = *(const uint4*)(zlane + ((size_t)((unsigned)srcs[k]) << 8));
            }
            #pragma unroll
            for (int k = 0; k < U; ++k) {
                acc_u32(u[k].x, acc[k & 1][0], acc[k & 1][1]);
                acc_u32(u[k].y, acc[k & 1][2], acc[k & 1][3]);
                acc_u32(u[k].z, acc[k & 1][4], acc[k & 1][5]);
                acc_u32(u[k].w, acc[k & 1][6], acc[k & 1][7]);
            }
        } else {
            uint2 u[U];
            #pragma unroll
            for (int k = 0; k < U; ++k) {
                u[k] = make_uint2(0u, 0u);
                if (srcs[k] >= 0)
                    u[k] = *(const uint2*)(zlane + ((size_t)((unsigned)srcs[k]) << 7));
            }
            #pragma unroll
            for (int k = 0; k < U; ++k) {
                acc_u32(u[k].x, acc[k & 1][0], acc[k & 1][1]);
                acc_u32(u[k].y, acc[k & 1][2], acc[k & 1][3]);
            }
        }
    }

    float id = inv_deg[n];
    const f32x4* Sp = (const f32x4*)(S + (size_t)n * D) + fl * NV;
    float4*      Op = (float4*)(out + (size_t)n * D) + fl * NV;
    float v[PF];
    #pragma unroll
    for (int q = 0; q < NV; ++q) {
        f32x4 s4 = __builtin_nontemporal_load(Sp + q);
        v[q * 4 + 0] = s4[0] + id * (acc[0][q * 4 + 0] + acc[1][q * 4 + 0]);
        v[q * 4 + 1] = s4[1] + id * (acc[0][q * 4 + 1] + acc[1][q * 4 + 1]);
        v[q * 4 + 2] = s4[2] + id * (acc[0][q * 4 + 2] + acc[1][q * 4 + 2]);
        v[q * 4 + 3] = s4[3] + id * (acc[0][q * 4 + 3] + acc[1][q * 4 + 3]);
    }

    if constexpr (ACT == 0) {
        #pragma unroll
        for (int q = 0; q < NV; ++q) {
            float4 o;
            o.x = fmaxf(v[q * 4 + 0], 0.f);
            o.y = fmaxf(v[q * 4 + 1], 0.f);
            o.z = fmaxf(v[q * 4 + 2], 0.f);
            o.w = fmaxf(v[q * 4 + 3], 0.f);
            Op[q] = o;
        }
    } else {
        // softmax across 16 lanes x 4 vals (D == 64)
        float m = fmaxf(fmaxf(v[0], v[1]), fmaxf(v[2], v[3]));
        #pragma unroll
        for (int off = 8; off > 0; off >>= 1) m = fmaxf(m, __shfl_xor(m, off, 16));
        float e0 = __expf(v[0] - m), e1 = __expf(v[1] - m);
        float e2 = __expf(v[2] - m), e3 = __expf(v[3] - m);
        float s = (e0 + e1) + (e2 + e3);
        #pragma unroll
        for (int off = 8; off > 0; off >>= 1) s += __shfl_xor(s, off, 16);
        float inv = 1.0f / s;
        float4 o;
        o.x = e0 * inv; o.y = e1 * inv; o.z = e2 * inv; o.w = e3 * inv;
        Op[0] = o;
    }
}

// ---------------------------------------------------------------------------
extern "C" void kernel_launch(void* const* d_in, const int* in_sizes, int n_in,
                              void* d_out, int out_size, void* d_ws, size_t ws_size,
                              hipStream_t stream) {
    const float* in_feat = (const float*)d_in[0];
    const int*   src     = (const int*)d_in[1];
    const int*   dst     = (const int*)d_in[2];
    const float* w1s = (const float*)d_in[3];
    const float* w1n = (const float*)d_in[4];
    const float* b1  = (const float*)d_in[5];
    const float* w2s = (const float*)d_in[6];
    const float* w2n = (const float*)d_in[7];
    const float* b2  = (const float*)d_in[8];
    const float* w3s = (const float*)d_in[9];
    const float* w3n = (const float*)d_in[10];
    const float* b3  = (const float*)d_in[11];

    const int N = N_NODES;
    const int E = in_sizes[1];

    char* p = (char*)d_ws;
    auto carve = [&](size_t bytes) -> char* {
        char* q = p;
        p += (bytes + 511) & ~(size_t)511;
        return q;
    };
    float*    S        = (float*)   carve((size_t)N * 128 * sizeof(float));
    ushort_t* Zb       = (ushort_t*)carve((size_t)N * 128 * sizeof(ushort_t));
    float*    H        = (float*)   carve((size_t)N * 128 * sizeof(float));
    int*      edge_src = (int*)     carve((size_t)E * sizeof(int));
    int*      row_ptr  = (int*)     carve((size_t)(N + 1) * sizeof(int));
    int*      cursor   = (int*)     carve((size_t)N * sizeof(int));
    int*      deg      = (int*)     carve((size_t)N * sizeof(int));
    float*    invd     = (float*)   carve((size_t)N * sizeof(float));
    int*      partials = (int*)     carve(256 * sizeof(int));
    int*      gcur     = (int*)     carve(MAXBUCK * sizeof(int));
    // staging pairs alias H (H is only written after scatter completes)
    long long* staged  = (long long*)H;
    // packed weights (hi/lo per matrix)
    ushort_t* P1sH = (ushort_t*)carve(128 * 128 * 2); ushort_t* P1sL = (ushort_t*)carve(128 * 128 * 2);
    ushort_t* P1nH = (ushort_t*)carve(128 * 128 * 2); ushort_t* P1nL = (ushort_t*)carve(128 * 128 * 2);
    ushort_t* P2sH = (ushort_t*)carve(128 * 64 * 2);  ushort_t* P2sL = (ushort_t*)carve(128 * 64 * 2);
    ushort_t* P2nH = (ushort_t*)carve(128 * 64 * 2);  ushort_t* P2nL = (ushort_t*)carve(128 * 64 * 2);
    ushort_t* P3sH = (ushort_t*)carve(64 * 64 * 2);   ushort_t* P3sL = (ushort_t*)carve(64 * 64 * 2);
    ushort_t* P3nH = (ushort_t*)carve(64 * 64 * 2);   ushort_t* P3nL = (ushort_t*)carve(64 * 64 * 2);

    // ---- weight packing (single launch, 28 blocks) ----
    pack_all<<<28, 256, 0, stream>>>(w1s, w1n, w2s, w2n, w3s, w3n,
                                     P1sH, P1sL, P1nH, P1nL,
                                     P2sH, P2sL, P2nH, P2nL,
                                     P3sH, P3sL, P3nH, P3nL);

    // ---- CSR build ----
    (void)hipMemsetAsync(deg, 0, (size_t)N * sizeof(int), stream);
    hist_kernel<<<(E + 255) / 256, 256, 0, stream>>>(dst, deg, E);
    const int NB = (N + 1023) / 1024;   // 98 segments
    scan_partial_sums<<<NB, 256, 0, stream>>>(deg, partials, N);
    scan_partials<<<1, 256, 0, stream>>>(partials, NB, row_ptr, N);
    scan_emit<<<NB, 256, 0, stream>>>(deg, partials, row_ptr, cursor, invd, gcur, N);
    const int NBUCK = (N + 255) >> 8;          // 391 buckets of 256 nodes
    const int BINB  = 256;
    const int CHUNK = (E + BINB - 1) / BINB;
    bin_pairs<<<BINB, 256, 0, stream>>>(src, dst, gcur, staged, E, NBUCK, CHUNK);
    scatter_bucket<<<NBUCK, 256, 0, stream>>>(staged, row_ptr, cursor, edge_src, N);

    const int GB = (N + 127) / 128;   // 782 row blocks
    const int AB = (N + 15) / 16;     // agg blocks: 16 nodes each

    // ---- Layer 1: 128 -> 128, relu ----
    mfma_gemm<128, 128><<<GB, 256, 0, stream>>>(in_feat, P1sH, P1sL, P1nH, P1nL, b1, S, Zb, N);
    agg_kernel<128, 0><<<AB, 256, 0, stream>>>(S, Zb, row_ptr, edge_src, invd, H, N);

    // ---- Layer 2: 128 -> 64, relu ----
    mfma_gemm<128, 64><<<GB, 256, 0, stream>>>(H, P2sH, P2sL, P2nH, P2nL, b2, S, Zb, N);
    agg_kernel<64, 0><<<AB, 256, 0, stream>>>(S, Zb, row_ptr, edge_src, invd, H, N);

    // ---- Layer 3: 64 -> 64, softmax ----
    mfma_gemm<64, 64><<<GB, 256, 0, stream>>>(H, P3sH, P3sL, P3nH, P3nL, b3, S, Zb, N);
    agg_kernel<64, 1><<<AB, 256, 0, stream>>>(S, Zb, row_ptr, edge_src, invd,
                                              (float*)d_out, N);
}

// Round 3
// 467.740 us; speedup vs baseline: 1.0189x; 1.0189x over previous
//
#include <hip/hip_runtime.h>
#include <hip/hip_bf16.h>

#define N_NODES 100000

typedef unsigned short ushort_t;
typedef __attribute__((ext_vector_type(8))) short short8;
typedef __attribute__((ext_vector_type(4))) float f32x4;

// ---------------------------------------------------------------------------
// helpers
// ---------------------------------------------------------------------------
static __device__ __forceinline__ ushort_t f2bf(float f) {
    unsigned u = __float_as_uint(f);
    unsigned r = u + 0x7FFFu + ((u >> 16) & 1u);   // round-to-nearest-even
    return (ushort_t)(r >> 16);
}
static __device__ __forceinline__ float bf2f(ushort_t h) {
    return __uint_as_float(((unsigned)h) << 16);
}

// split 8 contiguous fp32 into hi/lo bf16 fragments
static __device__ __forceinline__ void split8(const float* __restrict__ xp,
                                              short8& hi, short8& lo) {
    float4 x0 = *(const float4*)xp;
    float4 x1 = *(const float4*)(xp + 4);
    float xs[8] = {x0.x, x0.y, x0.z, x0.w, x1.x, x1.y, x1.z, x1.w};
    #pragma unroll
    for (int j = 0; j < 8; ++j) {
        ushort_t h = f2bf(xs[j]);
        hi[j] = (short)h;
        lo[j] = (short)f2bf(xs[j] - bf2f(h));
    }
}

// unpack-accumulate one u32 (2 bf16) into two fp32 accumulators
static __device__ __forceinline__ void acc_u32(unsigned w, float& a0, float& a1) {
    a0 += __uint_as_float(w << 16);
    a1 += __uint_as_float(w & 0xFFFF0000u);
}

// ---------------------------------------------------------------------------
// CSR build: histogram -> 3-phase scan -> bucket-binning -> exclusive scatter
// ---------------------------------------------------------------------------

// phase 1: per-block (1024-elem segment) total
__global__ __launch_bounds__(256) void scan_partial_sums(const int* __restrict__ deg,
                                                         int* __restrict__ partials, int N) {
    __shared__ int wsums[4];
    int tid = threadIdx.x, lane = tid & 63, wv = tid >> 6;
    int i0 = blockIdx.x * 1024 + tid * 4;
    int s = 0;
    #pragma unroll
    for (int j = 0; j < 4; ++j) {
        int i = i0 + j;
        if (i < N) s += deg[i];
    }
    #pragma unroll
    for (int off = 32; off > 0; off >>= 1) s += __shfl_xor(s, off, 64);
    if (lane == 0) wsums[wv] = s;
    __syncthreads();
    if (tid == 0)
        partials[blockIdx.x] = wsums[0] + wsums[1] + wsums[2] + wsums[3];
}

// phase 2: single block scans NB (<=256) partials -> exclusive, writes row_ptr[N]
__global__ __launch_bounds__(256) void scan_partials(int* __restrict__ partials, int NB,
                                                     int* __restrict__ row_ptr, int N) {
    __shared__ int wsums[4];
    int tid = threadIdx.x, lane = tid & 63, wv = tid >> 6;
    int v = (tid < NB) ? partials[tid] : 0;
    int x = v;
    #pragma unroll
    for (int off = 1; off < 64; off <<= 1) {
        int y = __shfl_up(x, off, 64);
        if (lane >= off) x += y;
    }
    if (lane == 63) wsums[wv] = x;
    __syncthreads();
    int woff = 0;
    for (int w = 0; w < wv; ++w) woff += wsums[w];
    int incl = x + woff;
    if (tid < NB) partials[tid] = incl - v;          // exclusive
    if (tid == NB - 1) row_ptr[N] = incl;            // grand total
}

// phase 3: emit row_ptr/cursor/invd; also init per-bucket cursor gcur
__global__ __launch_bounds__(256) void scan_emit(const int* __restrict__ deg,
                                                 const int* __restrict__ partials,
                                                 int* __restrict__ row_ptr,
                                                 int* __restrict__ cursor,
                                                 float* __restrict__ inv_deg,
                                                 int* __restrict__ gcur, int N) {
    __shared__ int wsums[4];
    int tid = threadIdx.x, lane = tid & 63, wv = tid >> 6;
    int i0 = blockIdx.x * 1024 + tid * 4;
    int d[4];
    #pragma unroll
    for (int j = 0; j < 4; ++j) {
        int i = i0 + j;
        d[j] = (i < N) ? deg[i] : 0;
    }
    int s = d[0] + d[1] + d[2] + d[3];
    int x = s;
    #pragma unroll
    for (int off = 1; off < 64; off <<= 1) {
        int y = __shfl_up(x, off, 64);
        if (lane >= off) x += y;
    }
    if (lane == 63) wsums[wv] = x;
    __syncthreads();
    int woff = 0;
    for (int w = 0; w < wv; ++w) woff += wsums[w];
    int run = partials[blockIdx.x] + woff + x - s;   // exclusive prefix of elem i0
    #pragma unroll
    for (int j = 0; j < 4; ++j) {
        int i = i0 + j;
        if (i < N) {
            row_ptr[i] = run;
            cursor[i]  = run;
            inv_deg[i] = 1.0f / (float)(d[j] > 0 ? d[j] : 1);
            if ((i & 255) == 0) gcur[i >> 8] = run;   // bucket staging base
            run += d[j];
        }
    }
}

// Phase A: bin (src,dst) pairs into bucket-ordered staging (bucket = dst>>8).
#define MAXBUCK 512
__global__ __launch_bounds__(256) void bin_pairs(const int* __restrict__ src,
                                                 const int* __restrict__ dst,
                                                 int* __restrict__ gcur,
                                                 long long* __restrict__ staged,
                                                 int E, int NBUCK, int C) {
    __shared__ int cnt[MAXBUCK];
    int tid = threadIdx.x;
    int e0 = blockIdx.x * C;
    int e1 = min(e0 + C, E);
    for (int b = tid; b < NBUCK; b += 256) cnt[b] = 0;
    __syncthreads();
    for (int e = e0 + tid; e < e1; e += 256) {
        int d = __builtin_nontemporal_load(&dst[e]);
        atomicAdd(&cnt[d >> 8], 1);
    }
    __syncthreads();
    for (int b = tid; b < NBUCK; b += 256) {
        int c = cnt[b];
        cnt[b] = (c > 0) ? atomicAdd(&gcur[b], c) : 0;   // now LDS cursor = global pos
    }
    __syncthreads();
    for (int e = e0 + tid; e < e1; e += 256) {
        int d = __builtin_nontemporal_load(&dst[e]);
        int s = __builtin_nontemporal_load(&src[e]);
        int p = atomicAdd(&cnt[d >> 8], 1);
        staged[p] = ((long long)d << 32) | (unsigned)s;   // hi=dst, lo=src
    }
}

// Phase B: one block per bucket; scatter within a private ~16KB edge_src window
__global__ __launch_bounds__(256) void scatter_bucket(const long long* __restrict__ staged,
                                                      const int* __restrict__ row_ptr,
                                                      int* __restrict__ cursor,
                                                      int* __restrict__ edge_src,
                                                      int N) {
    int b = blockIdx.x;
    int lo = b << 8;
    int hiN = min((b + 1) << 8, N);
    int gstart = row_ptr[lo];
    int gend   = row_ptr[hiN];
    for (int p = gstart + threadIdx.x; p < gend; p += 256) {
        long long pr = __builtin_nontemporal_load(&staged[p]);
        int d = (int)(pr >> 32);
        int s = (int)(pr & 0xFFFFFFFFll);
        int pos = atomicAdd(&cursor[d], 1);
        edge_src[pos] = s;
    }
}

// ---------------------------------------------------------------------------
// Weight pre-pack (6 matrices) MERGED with degree histogram: blocks 0..27 pack,
// blocks 28.. histogram (independent work; deg is zeroed by the prior memset).
// ---------------------------------------------------------------------------
__global__ __launch_bounds__(256) void pack_hist(
        const float* __restrict__ W0, const float* __restrict__ W1,
        const float* __restrict__ W2, const float* __restrict__ W3,
        const float* __restrict__ W4, const float* __restrict__ W5,
        ushort_t* H0, ushort_t* L0, ushort_t* H1, ushort_t* L1,
        ushort_t* H2, ushort_t* L2, ushort_t* H3, ushort_t* L3,
        ushort_t* H4, ushort_t* L4, ushort_t* H5, ushort_t* L5,
        const int* __restrict__ dst, int* __restrict__ deg, int E) {
    int b = blockIdx.x;
    if (b >= 28) {
        int e = (b - 28) * 256 + threadIdx.x;
        if (e < E) atomicAdd(&deg[__builtin_nontemporal_load(&dst[e])], 1);
        return;
    }
    const float* W; ushort_t* Hi; ushort_t* Lo; int K, NS, base;
    if (b < 8)       { W = W0; Hi = H0; Lo = L0; K = 128; NS = 128; base = 0;  }
    else if (b < 16) { W = W1; Hi = H1; Lo = L1; K = 128; NS = 128; base = 8;  }
    else if (b < 20) { W = W2; Hi = H2; Lo = L2; K = 128; NS = 64;  base = 16; }
    else if (b < 24) { W = W3; Hi = H3; Lo = L3; K = 128; NS = 64;  base = 20; }
    else if (b < 26) { W = W4; Hi = H4; Lo = L4; K = 64;  NS = 64;  base = 24; }
    else             { W = W5; Hi = H5; Lo = L5; K = 64;  NS = 64;  base = 26; }
    int tid = (b - base) * 256 + threadIdx.x;
    if (tid >= (K * NS) / 8) return;
    int l  = tid & 63;
    int fl = tid >> 6;
    int NT = NS / 16;
    int t = fl % NT, s = fl / NT;
    ushort_t hs[8], ls[8];
    #pragma unroll
    for (int j = 0; j < 8; ++j) {
        int k = s * 32 + (l >> 4) * 8 + j;
        int n = t * 16 + (l & 15);
        float w = W[(size_t)k * NS + n];
        ushort_t h = f2bf(w);
        hs[j] = h;
        ls[j] = f2bf(w - bf2f(h));
    }
    #pragma unroll
    for (int j = 0; j < 8; ++j) {
        Hi[(size_t)tid * 8 + j] = hs[j];
        Lo[(size_t)tid * 8 + j] = ls[j];
    }
}

// ---------------------------------------------------------------------------
// MFMA dual GEMM (split-bf16, fp32-grade) with LDS-transposed vector epilogue:
//   S[M,NS]  = X @ Ws + bias  (fp32 out, float4 stores)
//   Zb[M,NS] = X @ Wn         (bf16 out, uint2 stores)
// Per-wave private LDS staging (stride 20 words -> max 2-way bank alias, free;
// no barriers needed). R8 lesson: scalar epilogue stores caused 1.6x HBM write
// amplification + vmcnt stalls (123 MB vs 77 ideal, all pipes <25% busy).
// ---------------------------------------------------------------------------
template <int K, int NS>
__global__ __launch_bounds__(256) void mfma_gemm(const float* __restrict__ X,
                                                 const ushort_t* __restrict__ BsHi,
                                                 const ushort_t* __restrict__ BsLo,
                                                 const ushort_t* __restrict__ BnHi,
                                                 const ushort_t* __restrict__ BnLo,
                                                 const float* __restrict__ bias,
                                                 float* __restrict__ S,
                                                 ushort_t* __restrict__ Zb,
                                                 int M) {
    constexpr int KS = K / 32;      // mfma k-steps
    constexpr int NT = NS / 16;     // n-tiles
    __shared__ float ldsS[4][32 * 20];   // per-wave private transpose buffers
    __shared__ float ldsZ[4][32 * 20];
    int tid = threadIdx.x;
    int lane = tid & 63, w = tid >> 6;
    int baseM = blockIdx.x * 128 + w * 32;
    int rIn = lane & 15, q = lane >> 4;
    float* bufS = ldsS[w];
    float* bufZ = ldsZ[w];

    // ---- load + split all A fragments for this wave's 32 rows ----
    short8 Ahi[KS][2], Alo[KS][2];
    #pragma unroll
    for (int s = 0; s < KS; ++s) {
        #pragma unroll
        for (int mt = 0; mt < 2; ++mt) {
            int gm = baseM + mt * 16 + rIn;
            if (gm < M) {
                split8(&X[(size_t)gm * K + s * 32 + q * 8], Ahi[s][mt], Alo[s][mt]);
            } else {
                #pragma unroll
                for (int j = 0; j < 8; ++j) { Ahi[s][mt][j] = 0; Alo[s][mt][j] = 0; }
            }
        }
    }

    // ---- loop n-tiles; stream B frags from L2; 12 MFMA per (s,t) ----
    for (int t = 0; t < NT; ++t) {
        f32x4 aS0 = {0.f, 0.f, 0.f, 0.f}, aS1 = {0.f, 0.f, 0.f, 0.f};
        f32x4 aZ0 = {0.f, 0.f, 0.f, 0.f}, aZ1 = {0.f, 0.f, 0.f, 0.f};
        #pragma unroll
        for (int s = 0; s < KS; ++s) {
            size_t fo = ((size_t)(s * NT + t) * 64 + lane) * 8;
            short8 bsh = *(const short8*)&BsHi[fo];
            short8 bsl = *(const short8*)&BsLo[fo];
            short8 bnh = *(const short8*)&BnHi[fo];
            short8 bnl = *(const short8*)&BnLo[fo];
            aS0 = __builtin_amdgcn_mfma_f32_16x16x32_bf16(Ahi[s][0], bsh, aS0, 0, 0, 0);
            aS0 = __builtin_amdgcn_mfma_f32_16x16x32_bf16(Alo[s][0], bsh, aS0, 0, 0, 0);
            aS0 = __builtin_amdgcn_mfma_f32_16x16x32_bf16(Ahi[s][0], bsl, aS0, 0, 0, 0);
            aS1 = __builtin_amdgcn_mfma_f32_16x16x32_bf16(Ahi[s][1], bsh, aS1, 0, 0, 0);
            aS1 = __builtin_amdgcn_mfma_f32_16x16x32_bf16(Alo[s][1], bsh, aS1, 0, 0, 0);
            aS1 = __builtin_amdgcn_mfma_f32_16x16x32_bf16(Ahi[s][1], bsl, aS1, 0, 0, 0);
            aZ0 = __builtin_amdgcn_mfma_f32_16x16x32_bf16(Ahi[s][0], bnh, aZ0, 0, 0, 0);
            aZ0 = __builtin_amdgcn_mfma_f32_16x16x32_bf16(Alo[s][0], bnh, aZ0, 0, 0, 0);
            aZ0 = __builtin_amdgcn_mfma_f32_16x16x32_bf16(Ahi[s][0], bnl, aZ0, 0, 0, 0);
            aZ1 = __builtin_amdgcn_mfma_f32_16x16x32_bf16(Ahi[s][1], bnh, aZ1, 0, 0, 0);
            aZ1 = __builtin_amdgcn_mfma_f32_16x16x32_bf16(Alo[s][1], bnh, aZ1, 0, 0, 0);
            aZ1 = __builtin_amdgcn_mfma_f32_16x16x32_bf16(Ahi[s][1], bnl, aZ1, 0, 0, 0);
        }
        // ---- epilogue: C layout (col=rIn, row=q*4+r) -> LDS -> float4 stores
        #pragma unroll
        for (int r = 0; r < 4; ++r) {
            bufS[(q * 4 + r) * 20 + rIn]        = aS0[r];
            bufS[(16 + q * 4 + r) * 20 + rIn]   = aS1[r];
            bufZ[(q * 4 + r) * 20 + rIn]        = aZ0[r];
            bufZ[(16 + q * 4 + r) * 20 + rIn]   = aZ1[r];
        }
        int row = lane >> 2;            // 0..15
        int cq  = lane & 3;
        int col = t * 16 + cq * 4;
        float4 bv = *(const float4*)&bias[col];
        #pragma unroll
        for (int half = 0; half < 2; ++half) {
            int gm = baseM + half * 16 + row;
            float4 v = *(float4*)&bufS[(half * 16 + row) * 20 + cq * 4];
            float4 z = *(float4*)&bufZ[(half * 16 + row) * 20 + cq * 4];
            if (gm < M) {
                float4 o;
                o.x = v.x + bv.x; o.y = v.y + bv.y;
                o.z = v.z + bv.z; o.w = v.w + bv.w;
                *(float4*)&S[(size_t)gm * NS + col] = o;
                uint2 o2;
                o2.x = (unsigned)f2bf(z.x) | ((unsigned)f2bf(z.y) << 16);
                o2.y = (unsigned)f2bf(z.z) | ((unsigned)f2bf(z.w) << 16);
                *(uint2*)&Zb[(size_t)gm * NS + col] = o2;
            }
        }
    }
}

// ---------------------------------------------------------------------------
// Aggregate with bf16 Z: out[n,f] = act( S[n,f] + inv_deg[n]*sum Z[src,f] )
// R10: G = D/8 lanes per node (16 for D=128, 8 for D=64); every lane gathers
// 16B (uint4) so both layer widths use full-row 16B/lane gathers. Edge indices
// are loaded COOPERATIVELY (lane fl loads edge j+fl, one inst per G edges) and
// broadcast via __shfl width G -- removes the G-fold redundant same-address
// index loads that matched the gather instruction count in R9. S/invd loads
// hoisted above the gather loop to overlap with gather latency.
// ACT: 0 = relu, 1 = softmax across the 8-lane group (D=64 only)
// ---------------------------------------------------------------------------
template <int D, int ACT>
__global__ __launch_bounds__(256) void agg_kernel(const float* __restrict__ S,
                                                  const ushort_t* __restrict__ Zb,
                                                  const int* __restrict__ row_ptr,
                                                  const int* __restrict__ edge_src,
                                                  const float* __restrict__ inv_deg,
                                                  float* __restrict__ out, int N) {
    constexpr int G  = D / 8;          // lanes per node: 16 (D=128) / 8 (D=64)
    constexpr int PF = 8;              // floats per lane (both widths)
    constexpr int NG = 256 / G;        // nodes per block: 16 / 32
    constexpr int U  = G;              // edges per batch = lanes per group
    int tid = threadIdx.x;
    int g = tid / G, fl = tid % G;
    int n = blockIdx.x * NG + g;
    if (n >= N) return;
    int beg = row_ptr[n], end = row_ptr[n + 1];
    float id = inv_deg[n];

    // hoisted stream loads (overlap with gathers)
    const f32x4* Sp = (const f32x4*)(S + (size_t)n * D) + fl * 2;
    f32x4 s40 = __builtin_nontemporal_load(Sp);
    f32x4 s41 = __builtin_nontemporal_load(Sp + 1);

    float acc[2][PF];
    #pragma unroll
    for (int i = 0; i < PF; ++i) { acc[0][i] = 0.f; acc[1][i] = 0.f; }

    const char* zlane = (const char*)Zb + fl * 16;   // 16B per lane within row

    for (int j = beg; j < end; j += U) {
        int je = j + fl;
        int myS = (je < end) ? __builtin_nontemporal_load(&edge_src[je]) : -1;
        uint4 u[U];
        #pragma unroll
        for (int k = 0; k < U; ++k) {
            int s = __shfl(myS, k, U);   // broadcast within the G-lane group
            u[k] = make_uint4(0u, 0u, 0u, 0u);
            if (s >= 0)
                u[k] = *(const uint4*)(zlane + ((size_t)((unsigned)s) * (D * 2)));
        }
        #pragma unroll
        for (int k = 0; k < U; ++k) {
            acc_u32(u[k].x, acc[k & 1][0], acc[k & 1][1]);
            acc_u32(u[k].y, acc[k & 1][2], acc[k & 1][3]);
            acc_u32(u[k].z, acc[k & 1][4], acc[k & 1][5]);
            acc_u32(u[k].w, acc[k & 1][6], acc[k & 1][7]);
        }
    }

    float v[PF];
    #pragma unroll
    for (int i = 0; i < 4; ++i) {
        v[i]     = s40[i] + id * (acc[0][i]     + acc[1][i]);
        v[4 + i] = s41[i] + id * (acc[0][4 + i] + acc[1][4 + i]);
    }

    float4* Op = (float4*)(out + (size_t)n * D) + fl * 2;
    if constexpr (ACT == 0) {
        float4 o0, o1;
        o0.x = fmaxf(v[0], 0.f); o0.y = fmaxf(v[1], 0.f);
        o0.z = fmaxf(v[2], 0.f); o0.w = fmaxf(v[3], 0.f);
        o1.x = fmaxf(v[4], 0.f); o1.y = fmaxf(v[5], 0.f);
        o1.z = fmaxf(v[6], 0.f); o1.w = fmaxf(v[7], 0.f);
        Op[0] = o0; Op[1] = o1;
    } else {
        // softmax across 8 lanes x 8 vals (D == 64)
        float m = v[0];
        #pragma unroll
        for (int i = 1; i < 8; ++i) m = fmaxf(m, v[i]);
        #pragma unroll
        for (int off = 4; off > 0; off >>= 1) m = fmaxf(m, __shfl_xor(m, off, 8));
        float e[8], s = 0.f;
        #pragma unroll
        for (int i = 0; i < 8; ++i) { e[i] = __expf(v[i] - m); s += e[i]; }
        #pragma unroll
        for (int off = 4; off > 0; off >>= 1) s += __shfl_xor(s, off, 8);
        float inv = 1.0f / s;
        float4 o0, o1;
        o0.x = e[0] * inv; o0.y = e[1] * inv; o0.z = e[2] * inv; o0.w = e[3] * inv;
        o1.x = e[4] * inv; o1.y = e[5] * inv; o1.z = e[6] * inv; o1.w = e[7] * inv;
        Op[0] = o0; Op[1] = o1;
    }
}

// ---------------------------------------------------------------------------
extern "C" void kernel_launch(void* const* d_in, const int* in_sizes, int n_in,
                              void* d_out, int out_size, void* d_ws, size_t ws_size,
                              hipStream_t stream) {
    const float* in_feat = (const float*)d_in[0];
    const int*   src     = (const int*)d_in[1];
    const int*   dst     = (const int*)d_in[2];
    const float* w1s = (const float*)d_in[3];
    const float* w1n = (const float*)d_in[4];
    const float* b1  = (const float*)d_in[5];
    const float* w2s = (const float*)d_in[6];
    const float* w2n = (const float*)d_in[7];
    const float* b2  = (const float*)d_in[8];
    const float* w3s = (const float*)d_in[9];
    const float* w3n = (const float*)d_in[10];
    const float* b3  = (const float*)d_in[11];

    const int N = N_NODES;
    const int E = in_sizes[1];

    char* p = (char*)d_ws;
    auto carve = [&](size_t bytes) -> char* {
        char* q = p;
        p += (bytes + 511) & ~(size_t)511;
        return q;
    };
    float*    S        = (float*)   carve((size_t)N * 128 * sizeof(float));
    ushort_t* Zb       = (ushort_t*)carve((size_t)N * 128 * sizeof(ushort_t));
    float*    H        = (float*)   carve((size_t)N * 128 * sizeof(float));
    int*      edge_src = (int*)     carve((size_t)E * sizeof(int));
    int*      row_ptr  = (int*)     carve((size_t)(N + 1) * sizeof(int));
    int*      cursor   = (int*)     carve((size_t)N * sizeof(int));
    int*      deg      = (int*)     carve((size_t)N * sizeof(int));
    float*    invd     = (float*)   carve((size_t)N * sizeof(float));
    int*      partials = (int*)     carve(256 * sizeof(int));
    int*      gcur     = (int*)     carve(MAXBUCK * sizeof(int));
    // staging pairs alias H (H is only written after scatter completes)
    long long* staged  = (long long*)H;
    // packed weights (hi/lo per matrix)
    ushort_t* P1sH = (ushort_t*)carve(128 * 128 * 2); ushort_t* P1sL = (ushort_t*)carve(128 * 128 * 2);
    ushort_t* P1nH = (ushort_t*)carve(128 * 128 * 2); ushort_t* P1nL = (ushort_t*)carve(128 * 128 * 2);
    ushort_t* P2sH = (ushort_t*)carve(128 * 64 * 2);  ushort_t* P2sL = (ushort_t*)carve(128 * 64 * 2);
    ushort_t* P2nH = (ushort_t*)carve(128 * 64 * 2);  ushort_t* P2nL = (ushort_t*)carve(128 * 64 * 2);
    ushort_t* P3sH = (ushort_t*)carve(64 * 64 * 2);   ushort_t* P3sL = (ushort_t*)carve(64 * 64 * 2);
    ushort_t* P3nH = (ushort_t*)carve(64 * 64 * 2);   ushort_t* P3nL = (ushort_t*)carve(64 * 64 * 2);

    // ---- CSR build + weight packing (pack fused into hist launch) ----
    (void)hipMemsetAsync(deg, 0, (size_t)N * sizeof(int), stream);
    pack_hist<<<28 + (E + 255) / 256, 256, 0, stream>>>(
        w1s, w1n, w2s, w2n, w3s, w3n,
        P1sH, P1sL, P1nH, P1nL,
        P2sH, P2sL, P2nH, P2nL,
        P3sH, P3sL, P3nH, P3nL,
        dst, deg, E);
    const int NB = (N + 1023) / 1024;   // 98 segments
    scan_partial_sums<<<NB, 256, 0, stream>>>(deg, partials, N);
    scan_partials<<<1, 256, 0, stream>>>(partials, NB, row_ptr, N);
    scan_emit<<<NB, 256, 0, stream>>>(deg, partials, row_ptr, cursor, invd, gcur, N);
    const int NBUCK = (N + 255) >> 8;          // 391 buckets of 256 nodes
    const int BINB  = 256;
    const int CHUNK = (E + BINB - 1) / BINB;
    bin_pairs<<<BINB, 256, 0, stream>>>(src, dst, gcur, staged, E, NBUCK, CHUNK);
    scatter_bucket<<<NBUCK, 256, 0, stream>>>(staged, row_ptr, cursor, edge_src, N);

    const int GB   = (N + 127) / 128;   // 782 row blocks
    const int AB128 = (N + 15) / 16;    // agg blocks, D=128: 16 nodes each
    const int AB64  = (N + 31) / 32;    // agg blocks, D=64:  32 nodes each

    // ---- Layer 1: 128 -> 128, relu ----
    mfma_gemm<128, 128><<<GB, 256, 0, stream>>>(in_feat, P1sH, P1sL, P1nH, P1nL, b1, S, Zb, N);
    agg_kernel<128, 0><<<AB128, 256, 0, stream>>>(S, Zb, row_ptr, edge_src, invd, H, N);

    // ---- Layer 2: 128 -> 64, relu ----
    mfma_gemm<128, 64><<<GB, 256, 0, stream>>>(H, P2sH, P2sL, P2nH, P2nL, b2, S, Zb, N);
    agg_kernel<64, 0><<<AB64, 256, 0, stream>>>(S, Zb, row_ptr, edge_src, invd, H, N);

    // ---- Layer 3: 64 -> 64, softmax ----
    mfma_gemm<64, 64><<<GB, 256, 0, stream>>>(H, P3sH, P3sL, P3nH, P3nL, b3, S, Zb, N);
    agg_kernel<64, 1><<<AB64, 256, 0, stream>>>(S, Zb, row_ptr, edge_src, invd,
                                                (float*)d_out, N);
}